// Round 10
// baseline (77.011 us; speedup 1.0000x reference)
//
#include <hip/hip_runtime.h>

#define BATCH   8
#define SHAPE_N 8192
#define SKEL_M  2048
#define CHUNK   1024   // b-points per LDS chunk: 1024 * 32 B = 32 KB

// ws layout (floats):
//   [0, 256):         dir1 per-block partial sums (plain stores)
//   [256, 256+65536): dir2 partial mins, [quarter q<4][batch b<8][apt 2048]
// Every slot read by cd_reduce is written by cd_main in the same iteration,
// so no ws init and no atomics are needed (re-poison-safe).
#define WS2_OFF 256

// MFMA frag types (gfx950: 32x32x16 bf16 — A/B = 8 bf16 (4 VGPRs), C/D = 16 f32)
typedef short bf16x8 __attribute__((ext_vector_type(8)));
typedef float f32x16 __attribute__((ext_vector_type(16)));
union FragU { bf16x8 v; uint4 u4; };

// round-to-nearest-even f32 -> bf16 (result in low 16 bits)
__device__ __forceinline__ unsigned int f2bf(float a) {
    unsigned int u = __float_as_uint(a);
    return (u + 0x7FFFu + ((u >> 16) & 1u)) >> 16;
}
__device__ __forceinline__ float bf2f(unsigned int h) {
    return __uint_as_float(h << 16);
}
__device__ __forceinline__ unsigned int pack2(unsigned int lo, unsigned int hi) {
    return lo | (hi << 16);
}
// v ~= hi + lo (two bf16), residual ~2^-16 relative
__device__ __forceinline__ void bfsplit(float v, unsigned int& h, unsigned int& l) {
    h = f2bf(v);
    l = f2bf(v - bf2f(h));
}

// build the resident B-operand frag + fp32 |a|^2 for one a-point
template <int SA>
__device__ __forceinline__ void make_bfrag(
    const float* __restrict__ ap, int l, FragU& bf, float& ra)
{
    const float x = ap[0], y = ap[1], z = ap[2];
    ra = x * x + y * y + z * z;
    unsigned int hx, lx, hy, ly, hz, lz;
    bfsplit(x, hx, lx); bfsplit(y, hy, ly); bfsplit(z, hz, lz);
    const unsigned int one = 0x3F80u;
    if (l < 32) {   // k=0..7: (a_hi, 1, a_lo, 1)
        bf.u4 = make_uint4(pack2(hx, hy), pack2(hz, one),
                           pack2(lx, ly), pack2(lz, one));
    } else {        // k=8..15: (a_hi, 0, 0, 0)
        bf.u4 = make_uint4(pack2(hx, hy), pack2(hz, 0u), 0u, 0u);
    }
}

__device__ __forceinline__ float min16(const f32x16& D) {
    const float t0 = fminf(fminf(D[0],  D[1]),  D[2]);
    const float t1 = fminf(fminf(D[3],  D[4]),  D[5]);
    const float t2 = fminf(fminf(D[6],  D[7]),  D[8]);
    const float t3 = fminf(fminf(D[9],  D[10]), D[11]);
    const float t4 = fminf(fminf(D[12], D[13]), D[14]);
    const float u0 = fminf(fminf(t0, t1), t2);
    const float u1 = fminf(fminf(t3, t4), D[15]);
    return fminf(u0, u1);
}

// ---------------------------------------------------------------------------
// Scan 2048 b-points against this wave's 64 resident a-points (TWO B-frags
// per wave: each ds_read_b128 of the A-frag feeds 2 independent MFMAs —
// halves LDS traffic and doubles per-read issue work vs R9).
// D[m][n] = rb_m - 2 b_m.a_n via hi/lo bf16 split across K=16 (bit-identical
// to the passing R7-R9 kernels):
//   k=0..2  c_hi x a_hi   k=3 rb_hi x 1
//   k=4..6  c_hi x a_lo   k=7 rb_lo x 1
//   k=8..10 c_lo x a_hi   k=11..15 zero          (c = -2b; ra added in fp32)
// ---------------------------------------------------------------------------
template <int SA, int SB>
__device__ __forceinline__ void cd_scan2(
    const float* __restrict__ Araw,   // a-side: first of this wave's 64 points
    const float* __restrict__ Braw,   // b-side: 2048-point scan base
    uint4* sB, float& rmin0o, float& rmin1o, float& ra0o, float& ra1o)
{
    const int tid = threadIdx.x;
    const int l = tid & 63;

    FragU bf0, bf1;
    float ra0, ra1;
    make_bfrag<SA>(Araw + (size_t)(l & 31) * SA, l, bf0, ra0);
    make_bfrag<SA>(Araw + (size_t)(32 + (l & 31)) * SA, l, bf1, ra1);

    const f32x16 Z = {0,0,0,0,0,0,0,0,0,0,0,0,0,0,0,0};
    float rmin0 = 3.4e38f, rmin1 = 3.4e38f;
    const unsigned int off0 = (unsigned int)((l >> 5) * 512 + (l & 31) * 16);

    for (int c = 0; c < 2048; c += CHUNK) {
        __syncthreads();                       // previous chunk fully consumed
        const float* src = Braw + (size_t)c * SB;
        for (int i = tid; i < CHUNK; i += 256) {
            const float* q = src + (size_t)i * SB;
            const float bx = q[0], by = q[1], bz = q[2];
            const float cx = -2.f * bx, cy = -2.f * by, cz = -2.f * bz;
            const float rb = bx * bx + by * by + bz * bz;
            unsigned int chx, clx, chy, cly, chz, clz, rbh, rbl;
            bfsplit(cx, chx, clx); bfsplit(cy, chy, cly); bfsplit(cz, chz, clz);
            bfsplit(rb, rbh, rbl);
            const int g = i >> 5, r = i & 31;
            sB[g * 64 + r]      = make_uint4(pack2(chx, chy), pack2(chz, rbh),
                                             pack2(chx, chy), pack2(chz, rbl));
            sB[g * 64 + 32 + r] = make_uint4(pack2(clx, cly), pack2(clz, 0u),
                                             0u, 0u);
        }
        __syncthreads();

        unsigned int o = off0;
#pragma unroll 4
        for (int g = 0; g < CHUNK / 32; ++g) {
            FragU af;
            af.u4 = *(const uint4*)((const char*)sB + o);
            o += 1024;
            f32x16 D0 = __builtin_amdgcn_mfma_f32_32x32x16_bf16(af.v, bf0.v, Z, 0, 0, 0);
            f32x16 D1 = __builtin_amdgcn_mfma_f32_32x32x16_bf16(af.v, bf1.v, Z, 0, 0, 0);
            rmin0 = fminf(rmin0, min16(D0));
            rmin1 = fminf(rmin1, min16(D1));
        }
    }
    // lane l and l^32 cover complementary rows of the same col (a-point)
    rmin0o = fminf(rmin0, __shfl_xor(rmin0, 32, 64));
    rmin1o = fminf(rmin1, __shfl_xor(rmin1, 32, 64));
    ra0o = ra0; ra1o = ra1;
}

// ---------------------------------------------------------------------------
// 512 equal blocks (64 steps x 2 MFMA each), 2 blocks/CU, 8 waves/CU:
//   [0,256):   dir1 — a = shape (256 pts/block), b = full skel (2048).
//              Complete min => sqrt+block-sum => one partial to ws[bid].
//   [256,512): dir2 — a = skel (256 pts/block), b = one shape quarter (2048).
//              Partial min => plain stores into this quarter's ws slice.
// ---------------------------------------------------------------------------
__global__ __launch_bounds__(256) void cd_main(
    const float* __restrict__ shape, const float* __restrict__ skel,
    float* __restrict__ ws)
{
    __shared__ uint4 sB[CHUNK * 2];    // 32 KB
    __shared__ float s_wsum[4];
    const int tid = threadIdx.x;
    const int l = tid & 63, wv = tid >> 6;
    const int bid = blockIdx.x;

    if (bid < 256) {                   // dir1: a = shape (stride 6), b = skel (stride 3)
        const int b = bid >> 5, sub = bid & 31;
        float rmin0, rmin1, ra0, ra1;
        cd_scan2<6, 3>(shape + ((size_t)b * SHAPE_N + sub * 256 + wv * 64) * 6,
                       skel + (size_t)b * SKEL_M * 3,
                       sB, rmin0, rmin1, ra0, ra1);
        float d = (l < 32) ? sqrtf(fmaxf(ra0 + rmin0, 0.f)) +
                             sqrtf(fmaxf(ra1 + rmin1, 0.f)) : 0.f;
        for (int o = 32; o; o >>= 1) d += __shfl_down(d, o, 64);
        if (l == 0) s_wsum[wv] = d;
        __syncthreads();
        if (tid == 0)
            ws[bid] = s_wsum[0] + s_wsum[1] + s_wsum[2] + s_wsum[3];
    } else {                           // dir2: a = skel (stride 3), b = shape quarter (stride 6)
        const int j = bid - 256;
        const int b = j >> 5, rem = j & 31;
        const int asub = rem >> 2, q = rem & 3;
        float rmin0, rmin1, ra0, ra1;
        cd_scan2<3, 6>(skel + ((size_t)b * SKEL_M + asub * 256 + wv * 64) * 3,
                       shape + ((size_t)b * SHAPE_N + q * 2048) * 6,
                       sB, rmin0, rmin1, ra0, ra1);
        if (l < 32) {
            float* w = ws + WS2_OFF + q * (BATCH * SKEL_M) + b * SKEL_M +
                       asub * 256 + wv * 64;
            w[l]      = ra0 + rmin0;
            w[32 + l] = ra1 + rmin1;
        }
    }
}

// ---------------------------------------------------------------------------
// Single-block reduce (no atomics, no pre-zeroed out): min-fold the 4 dir2
// quarters (float4 loads over 256 KB, L2-resident), clamp+sqrt+sum, add the
// 256 dir1 partials, write out[0].
// ---------------------------------------------------------------------------
__global__ __launch_bounds__(1024) void cd_reduce(
    const float* __restrict__ ws, float* __restrict__ out)
{
    __shared__ float s_wsum[16];
    const int t = threadIdx.x;
    float s = 0.f;

    const float4* w4 = (const float4*)(ws + WS2_OFF);
#pragma unroll
    for (int r = 0; r < 4; ++r) {
        const int i4 = r * 1024 + t;          // float4 index within 4096
        float4 v0 = w4[i4];
        const float4 v1 = w4[4096 + i4];
        const float4 v2 = w4[8192 + i4];
        const float4 v3 = w4[12288 + i4];
        v0.x = fminf(fminf(v0.x, v1.x), fminf(v2.x, v3.x));
        v0.y = fminf(fminf(v0.y, v1.y), fminf(v2.y, v3.y));
        v0.z = fminf(fminf(v0.z, v1.z), fminf(v2.z, v3.z));
        v0.w = fminf(fminf(v0.w, v1.w), fminf(v2.w, v3.w));
        s += sqrtf(fmaxf(v0.x, 0.f)) + sqrtf(fmaxf(v0.y, 0.f)) +
             sqrtf(fmaxf(v0.z, 0.f)) + sqrtf(fmaxf(v0.w, 0.f));
    }
    if (t < 256) s += ws[t];                  // dir1 per-block partial sums

    for (int o = 32; o; o >>= 1) s += __shfl_down(s, o, 64);
    const int lane = t & 63, wave = t >> 6;
    if (lane == 0) s_wsum[wave] = s;
    __syncthreads();
    if (t == 0) {
        float tot = 0.f;
#pragma unroll
        for (int w = 0; w < 16; ++w) tot += s_wsum[w];
        out[0] = tot * 1e-4f;
    }
}

extern "C" void kernel_launch(void* const* d_in, const int* in_sizes, int n_in,
                              void* d_out, int out_size, void* d_ws, size_t ws_size,
                              hipStream_t stream) {
    const float* shape = (const float*)d_in[0];   // (8, 8192, 6) — use first 3
    const float* skel  = (const float*)d_in[1];   // (8, 2048, 3)
    float* out         = (float*)d_out;           // scalar
    float* ws          = (float*)d_ws;            // 65792 floats = 257 KB

    cd_main<<<512, 256, 0, stream>>>(shape, skel, ws);
    cd_reduce<<<1, 1024, 0, stream>>>(ws, out);
}